// Round 7
// baseline (508.472 us; speedup 1.0000x reference)
//
#include <hip/hip_runtime.h>
#include <hip/hip_cooperative_groups.h>

namespace cg = cooperative_groups;

#define Bsz 1024
#define Nn 256
#define Fdim 8
#define Eedge 1024
#define OUTC 128
#define CADV 192
#define CTOT 256
#define Ktot 32768   // Nn * OUTC
#define ASTR 40      // LDS row stride in bf16 (32+8): 80 B = 5*16, aligned, 2-way banks

typedef __attribute__((ext_vector_type(8))) short short8;
typedef __attribute__((ext_vector_type(4))) float float4v;

static __device__ inline unsigned short f2bf(float f) {
  union { float f; unsigned u; } v; v.f = f;
  unsigned r = v.u + 0x7FFFu + ((v.u >> 16) & 1u);  // round-nearest-even
  return (unsigned short)(r >> 16);
}
static __device__ inline uint4 pack8(const unsigned short* b) {
  uint4 v;
  v.x = (unsigned)b[0] | ((unsigned)b[1] << 16);
  v.y = (unsigned)b[2] | ((unsigned)b[3] << 16);
  v.z = (unsigned)b[4] | ((unsigned)b[5] << 16);
  v.w = (unsigned)b[6] | ((unsigned)b[7] << 16);
  return v;
}

// ===========================================================================
// Cooperative mega-kernel: P0 prep -> P1 feat -> P2 gemm(atomic part) -> P3.
// All phases are work-loops over fixed unit counts, so any grid size works.
// ===========================================================================
__global__ __launch_bounds__(256, 2) void mega(
    const float* __restrict__ x, const int* __restrict__ ei,
    const float* __restrict__ w1, const float* __restrict__ b1,
    const float* __restrict__ w2, const float* __restrict__ b2,
    const float* __restrict__ rootw, const float* __restrict__ convb,
    const float* __restrict__ advw, const float* __restrict__ advb,
    const float* __restrict__ v1w, const float* __restrict__ v1b,
    const float* __restrict__ v2w, const float* __restrict__ v2b,
    const float* __restrict__ v3w, const float* __restrict__ v3b,
    float* __restrict__ out,
    unsigned short* __restrict__ wt, unsigned short* __restrict__ feat,
    float* __restrict__ part, float* __restrict__ msg)
{
  __shared__ __align__(16) char smem[49152];  // union across phases (48 KB)
  cg::grid_group grid = cg::this_grid();
  int bid = blockIdx.x, t = threadIdx.x;
  int nblk = gridDim.x;

  // ---------------- P0: wt transpose + part zero + (block0) theta/S/msg ----
  {
    unsigned short* st = (unsigned short*)smem;  // 20 KB
    for (int kt = bid; kt < 1024; kt += nblk) {
      int c = t;
      const float* src; int stride, col;
      if (c < CADV) { src = advw; stride = CADV; col = c; }
      else          { src = v1w;  stride = 64;   col = c - CADV; }
      for (int p = 0; p < 4; ++p) {
        unsigned short buf[8];
#pragma unroll
        for (int i = 0; i < 8; ++i)
          buf[i] = f2bf(src[(size_t)(kt * 32 + p * 8 + i) * stride + col]);
        *(uint4*)(st + c * ASTR + p * 8) = pack8(buf);
      }
      __syncthreads();
      uint4* dst = (uint4*)(wt + (size_t)kt * (CTOT * 32));
      for (int r = 0; r < 4; ++r) {
        int s = r * 256 + c;
        dst[s] = *(const uint4*)(st + (s >> 2) * ASTR + (s & 3) * 8);
      }
      __syncthreads();
    }
    // zero the 1 MiB atomic accumulator
    float4 z4 = make_float4(0.f, 0.f, 0.f, 0.f);
    for (int i = bid * 256 + t; i < Bsz * CTOT / 4; i += nblk * 256)
      ((float4*)part)[i] = z4;
    if (bid == 0) {  // theta (edge-MLP, identical per edge), scatter S, msg
      float* h_s     = (float*)smem;            // 64 f
      float* theta_s = (float*)(smem + 256);    // 1024 f
      float* S_s     = (float*)(smem + 4352);   // 2048 f (ends 12544)
      int*   flag    = (int*)(smem + 12544);
      if (t < 64) h_s[t] = fmaxf(w1[t] + b1[t], 0.f);
      for (int i = t; i < Nn * Fdim; i += 256) S_s[i] = 0.f;
      if (t == 0) {
        int z = 0;
        for (int i = 1; i < 16; i += 2) z |= ei[i];
        *flag = (z == 0);  // little-endian int64 detection
      }
      __syncthreads();
      int is64 = *flag;
      for (int i = 0; i < 4; ++i) {
        int c = t + i * 256;
        float acc = b2[c];
#pragma unroll
        for (int j = 0; j < 64; ++j) acc += h_s[j] * w2[j * 1024 + c];
        theta_s[c] = acc;
      }
      for (int e = t; e < Eedge; e += 256) {
        int src, tgt;
        if (is64) { src = ei[2 * e]; tgt = ei[2 * (Eedge + e)]; }
        else      { src = ei[e];     tgt = ei[Eedge + e]; }
        src &= 255; tgt &= 255;
#pragma unroll
        for (int f = 0; f < Fdim; ++f)
          atomicAdd(&S_s[tgt * Fdim + f], x[src * Fdim + f]);
      }
      __syncthreads();
      for (int i = 0; i < 128; ++i) {
        int idx = i * 256 + t;
        int n = idx >> 7, o = idx & 127;
        float m = 0.f;
#pragma unroll
        for (int f = 0; f < Fdim; ++f) m += S_s[n * Fdim + f] * theta_s[f * 128 + o];
        msg[idx] = m;
      }
    }
  }
  grid.sync();

  // ---------------- P1: feat bf16 -> feat[kt][b][32] ------------------------
  {
    float* rw_s  = (float*)smem;                       // 4 KB
    float* cb_s  = (float*)(smem + 4096);              // 512 B
    float* msg_s = (float*)(smem + 4608);              // 2 KB (4 nodes x 128)
    unsigned short* st = (unsigned short*)(smem + 8192);  // 40960 B
    for (int i = t; i < Fdim * OUTC; i += 256) rw_s[i] = rootw[i];
    if (t < OUTC) cb_s[t] = convb[t];
    for (int u = bid; u < 512; u += nblk) {
      int nb = u >> 3, by = u & 7;   // 4-node group, 128-batch chunk
      __syncthreads();
      if (by == 0)
        for (int i = t; i < 512; i += 256) msg_s[i] = msg[nb * 512 + i];
      __syncthreads();
      int bl = t & 127, oh = t >> 7;
      int b = by * 128 + bl;
      bool isb0 = (b == 0);
      const float* xp = x + ((size_t)b * Nn + nb * 4) * Fdim;
      float xr[32];
#pragma unroll
      for (int p = 0; p < 8; ++p) *(float4*)(xr + 4 * p) = ((const float4*)xp)[p];
      for (int node = 0; node < 4; ++node) {
        for (int r = 0; r < 2; ++r) {
          int obase = oh * 64 + r * 32;
          int ktl = oh * 2 + r;
          for (int p = 0; p < 4; ++p) {
            unsigned short buf[8];
#pragma unroll
            for (int jj = 0; jj < 8; ++jj) {
              int o = obase + p * 8 + jj;
              float v = cb_s[o];
#pragma unroll
              for (int f = 0; f < Fdim; ++f) v += xr[node * 8 + f] * rw_s[f * OUTC + o];
              if (isb0) v += msg_s[node * OUTC + o];
              buf[jj] = f2bf(fmaxf(v, 0.f));
            }
            *(uint4*)(st + (ktl * 128 + bl) * ASTR + p * 8) = pack8(buf);
          }
        }
        __syncthreads();
        int kt0 = (nb * 4 + node) * 4;
        for (int ktl = 0; ktl < 4; ++ktl) {
          uint4* dst = (uint4*)(feat + (((size_t)(kt0 + ktl)) * Bsz + by * 128) * 32);
          for (int p = 0; p < 2; ++p) {
            int s = p * 256 + t;   // lane-consecutive -> coalesced
            dst[s] = *(const uint4*)(st + (ktl * 128 + (s >> 2)) * ASTR + (s & 3) * 8);
          }
        }
        __syncthreads();
      }
    }
  }
  grid.sync();

  // ---------------- P2: MFMA GEMM, atomic fp32 accumulate into part ---------
  {
    short* a_s = (short*)smem;           // 64*ASTR  = 5120 B
    short* b_s = (short*)(smem + 5120);  // 256*ASTR = 20480 B
    int wave = t >> 6, lane = t & 63;
    int lm = lane & 15, lq = lane >> 4;
    for (int u = bid; u < 512; u += nblk) {
      int mb = u >> 5, ch = u & 31;      // 16 m-tiles x 32 K-chunks
      float4v acc[4][4];
#pragma unroll
      for (int i = 0; i < 4; ++i)
#pragma unroll
        for (int j = 0; j < 4; ++j) acc[i][j] = (float4v)0.f;
      for (int kk = 0; kk < 32; ++kk) {
        int kt = ch * 32 + kk;
        const uint4* gB = (const uint4*)wt + (size_t)kt * 1024;
        const uint4* gA = (const uint4*)feat + (size_t)kt * 4096 + mb * 256;
        uint4 vb[4];
#pragma unroll
        for (int p = 0; p < 4; ++p) vb[p] = gB[t + 256 * p];
        uint4 va = gA[t];
        __syncthreads();  // previous tile consumed (also guards phase entry)
#pragma unroll
        for (int p = 0; p < 4; ++p) {
          int uu = t + 256 * p;
          *(uint4*)(b_s + (uu >> 2) * ASTR + (uu & 3) * 8) = vb[p];
        }
        *(uint4*)(a_s + (t >> 2) * ASTR + (t & 3) * 8) = va;
        __syncthreads();
        short8 aF[4];
#pragma unroll
        for (int i = 0; i < 4; ++i)
          aF[i] = *(const short8*)(a_s + (i * 16 + lm) * ASTR + lq * 8);
#pragma unroll
        for (int j = 0; j < 4; ++j) {
          short8 bF = *(const short8*)(b_s + (wave * 64 + j * 16 + lm) * ASTR + lq * 8);
#pragma unroll
          for (int i = 0; i < 4; ++i)
            acc[i][j] = __builtin_amdgcn_mfma_f32_16x16x32_bf16(aF[i], bF, acc[i][j], 0, 0, 0);
        }
      }
      float* pr = part + (size_t)mb * 64 * CTOT;
#pragma unroll
      for (int i = 0; i < 4; ++i)
#pragma unroll
        for (int r = 0; r < 4; ++r)
#pragma unroll
          for (int j = 0; j < 4; ++j)
            atomicAdd(&pr[(i * 16 + lq * 4 + r) * CTOT + wave * 64 + j * 16 + lm],
                      acc[i][j][r]);
    }
  }
  __threadfence();
  grid.sync();

  // ---------------- P3: biases+relu, val MLP, dueling combine ---------------
  {
    float* adv_s  = (float*)smem;
    float* v1_s   = (float*)(smem + 768);
    float* val2_s = (float*)(smem + 1024);
    float* val3_s = (float*)(smem + 1280);
    for (int b = bid; b < Bsz; b += nblk) {
      __syncthreads();
      float s = part[(size_t)b * CTOT + t];
      if (t < CADV) adv_s[t] = fmaxf(s + advb[t], 0.f);
      else          v1_s[t - CADV] = fmaxf(s + v1b[t - CADV], 0.f);
      __syncthreads();
      if (t < 64) {
        float a = v2b[t];
#pragma unroll
        for (int i = 0; i < 64; ++i) a += v1_s[i] * v2w[i * 64 + t];
        val2_s[t] = fmaxf(a, 0.f);
      }
      __syncthreads();
      if (t < 64) {
        float a = v3b[t];
#pragma unroll
        for (int j = 0; j < 64; ++j) a += val2_s[j] * v3w[j * 64 + t];
        val3_s[t] = a;
      }
      __syncthreads();
      if (t < CADV) {
        int d = t / 3;
        float mean = (adv_s[d * 3] + adv_s[d * 3 + 1] + adv_s[d * 3 + 2]) * (1.f / 3.f);
        out[(size_t)b * CADV + t] = val3_s[d] + adv_s[t] - mean;
      }
    }
  }
}

// ===========================================================================
// Fallback path (R6 pipeline, proven-correct) if cooperative launch fails.
// ===========================================================================
__global__ __launch_bounds__(256) void prep_kernel(
    const float* __restrict__ advw, const float* __restrict__ v1w,
    const float* __restrict__ w1, const float* __restrict__ b1,
    const float* __restrict__ w2, const float* __restrict__ b2,
    const float* __restrict__ x, const int* __restrict__ ei,
    unsigned short* __restrict__ wt, float* __restrict__ theta_ws,
    float* __restrict__ S_ws)
{
  int bid = blockIdx.x, t = threadIdx.x;
  if (bid < 1024) {
    __shared__ unsigned short st[CTOT * ASTR];
    int kt = bid, c = t;
    const float* src; int stride, col;
    if (c < CADV) { src = advw; stride = CADV; col = c; }
    else          { src = v1w;  stride = 64;   col = c - CADV; }
    for (int p = 0; p < 4; ++p) {
      unsigned short buf[8];
#pragma unroll
      for (int i = 0; i < 8; ++i)
        buf[i] = f2bf(src[(size_t)(kt * 32 + p * 8 + i) * stride + col]);
      *(uint4*)(st + c * ASTR + p * 8) = pack8(buf);
    }
    __syncthreads();
    uint4* dst = (uint4*)(wt + (size_t)kt * (CTOT * 32));
    for (int r = 0; r < 4; ++r) {
      int s = r * 256 + c;
      dst[s] = *(const uint4*)(st + (s >> 2) * ASTR + (s & 3) * 8);
    }
  } else if (bid < 1032) {
    __shared__ float h_s[64];
    if (t < 64) h_s[t] = fmaxf(w1[t] + b1[t], 0.f);
    __syncthreads();
    if (t < 128) {
      int c = (bid - 1024) * 128 + t;
      float acc = b2[c];
#pragma unroll
      for (int j = 0; j < 64; ++j) acc += h_s[j] * w2[j * 1024 + c];
      theta_ws[c] = acc;
    }
  } else {
    __shared__ float S_s[Nn * Fdim];
    __shared__ int is64_s;
    for (int i = t; i < Nn * Fdim; i += 256) S_s[i] = 0.f;
    if (t == 0) {
      int z = 0;
      for (int i = 1; i < 16; i += 2) z |= ei[i];
      is64_s = (z == 0);
    }
    __syncthreads();
    int is64 = is64_s;
    for (int e = t; e < Eedge; e += 256) {
      int src, tgt;
      if (is64) { src = ei[2 * e]; tgt = ei[2 * (Eedge + e)]; }
      else      { src = ei[e];     tgt = ei[Eedge + e]; }
      src &= 255; tgt &= 255;
#pragma unroll
      for (int f = 0; f < Fdim; ++f)
        atomicAdd(&S_s[tgt * Fdim + f], x[src * Fdim + f]);
    }
    __syncthreads();
    for (int i = t; i < Nn * Fdim; i += 256) S_ws[i] = S_s[i];
  }
}

__global__ __launch_bounds__(256) void feat_kernel(
    const float* __restrict__ x, const float* __restrict__ rootw,
    const float* __restrict__ convb, const float* __restrict__ theta_ws,
    const float* __restrict__ S_ws, unsigned short* __restrict__ feat)
{
  __shared__ float rw_s[Fdim * OUTC];
  __shared__ float cb_s[OUTC];
  __shared__ float th_s[1024];
  __shared__ float Ssh[32];
  __shared__ float msg_s[4][OUTC];
  __shared__ unsigned short st[4 * 128 * ASTR];
  int nb = blockIdx.x, by = blockIdx.y, t = threadIdx.x;
  for (int i = t; i < Fdim * OUTC; i += 256) rw_s[i] = rootw[i];
  if (t < OUTC) cb_s[t] = convb[t];
  if (by == 0) {
    for (int i = t; i < 1024; i += 256) th_s[i] = theta_ws[i];
    if (t < 32) Ssh[t] = S_ws[nb * 32 + t];
  }
  __syncthreads();
  if (by == 0) {
#pragma unroll
    for (int p = 0; p < 2; ++p) {
      int idx = p * 256 + t;
      int node = idx >> 7, o = idx & 127;
      float m = 0.f;
#pragma unroll
      for (int f = 0; f < Fdim; ++f) m += Ssh[node * 8 + f] * th_s[f * 128 + o];
      msg_s[node][o] = m;
    }
  }
  __syncthreads();
  int bl = t & 127, oh = t >> 7;
  int b = by * 128 + bl;
  bool isb0 = (b == 0);
  const float* xp = x + ((size_t)b * Nn + nb * 4) * Fdim;
  float xr[32];
#pragma unroll
  for (int p = 0; p < 8; ++p) *(float4*)(xr + 4 * p) = ((const float4*)xp)[p];
  for (int node = 0; node < 4; ++node) {
    for (int r = 0; r < 2; ++r) {
      int obase = oh * 64 + r * 32;
      int ktl = oh * 2 + r;
      for (int p = 0; p < 4; ++p) {
        unsigned short buf[8];
#pragma unroll
        for (int jj = 0; jj < 8; ++jj) {
          int o = obase + p * 8 + jj;
          float v = cb_s[o];
#pragma unroll
          for (int f = 0; f < Fdim; ++f) v += xr[node * 8 + f] * rw_s[f * OUTC + o];
          if (isb0) v += msg_s[node][o];
          buf[jj] = f2bf(fmaxf(v, 0.f));
        }
        *(uint4*)(st + (ktl * 128 + bl) * ASTR + p * 8) = pack8(buf);
      }
    }
    __syncthreads();
    int kt0 = (nb * 4 + node) * 4;
    for (int ktl = 0; ktl < 4; ++ktl) {
      uint4* dst = (uint4*)(feat + (((size_t)(kt0 + ktl)) * Bsz + by * 128) * 32);
      for (int p = 0; p < 2; ++p) {
        int s = p * 256 + t;
        dst[s] = *(const uint4*)(st + (ktl * 128 + (s >> 2)) * ASTR + (s & 3) * 8);
      }
    }
    __syncthreads();
  }
}

__global__ __launch_bounds__(256, 3) void gemm_fb(
    const unsigned short* __restrict__ feat, const unsigned short* __restrict__ wt,
    float* __restrict__ part, int iters)
{
  __shared__ short a_s[64 * ASTR];
  __shared__ short b_s[256 * ASTR];
  int t = threadIdx.x;
  int mb = blockIdx.x, ch = blockIdx.y;
  int wave = t >> 6, lane = t & 63;
  int lm = lane & 15, lq = lane >> 4;
  float4v acc[4][4];
#pragma unroll
  for (int i = 0; i < 4; ++i)
#pragma unroll
    for (int j = 0; j < 4; ++j) acc[i][j] = (float4v)0.f;
  for (int kk = 0; kk < iters; ++kk) {
    int kt = ch * iters + kk;
    const uint4* gB = (const uint4*)wt + (size_t)kt * 1024;
    const uint4* gA = (const uint4*)feat + (size_t)kt * 4096 + mb * 256;
    uint4 vb[4];
#pragma unroll
    for (int p = 0; p < 4; ++p) vb[p] = gB[t + 256 * p];
    uint4 va = gA[t];
    __syncthreads();
#pragma unroll
    for (int p = 0; p < 4; ++p) {
      int u = t + 256 * p;
      *(uint4*)(b_s + (u >> 2) * ASTR + (u & 3) * 8) = vb[p];
    }
    *(uint4*)(a_s + (t >> 2) * ASTR + (t & 3) * 8) = va;
    __syncthreads();
    short8 aF[4];
#pragma unroll
    for (int i = 0; i < 4; ++i)
      aF[i] = *(const short8*)(a_s + (i * 16 + lm) * ASTR + lq * 8);
#pragma unroll
    for (int j = 0; j < 4; ++j) {
      short8 bF = *(const short8*)(b_s + (wave * 64 + j * 16 + lm) * ASTR + lq * 8);
#pragma unroll
      for (int i = 0; i < 4; ++i)
        acc[i][j] = __builtin_amdgcn_mfma_f32_16x16x32_bf16(aF[i], bF, acc[i][j], 0, 0, 0);
    }
  }
  float* pr = part + (size_t)mb * 64 * CTOT;
#pragma unroll
  for (int i = 0; i < 4; ++i)
#pragma unroll
    for (int r = 0; r < 4; ++r)
#pragma unroll
      for (int j = 0; j < 4; ++j)
        atomicAdd(&pr[(i * 16 + lq * 4 + r) * CTOT + wave * 64 + j * 16 + lm],
                  acc[i][j][r]);
}

__global__ __launch_bounds__(256) void zero_kernel(float* __restrict__ part) {
  ((float4*)part)[blockIdx.x * 256 + threadIdx.x] = make_float4(0.f, 0.f, 0.f, 0.f);
}

__global__ __launch_bounds__(256) void final_kernel(
    const float* __restrict__ part,
    const float* __restrict__ advb, const float* __restrict__ v1b,
    const float* __restrict__ v2w, const float* __restrict__ v2b,
    const float* __restrict__ v3w, const float* __restrict__ v3b,
    float* __restrict__ out)
{
  __shared__ float adv_s[CADV];
  __shared__ float v1_s[64];
  __shared__ float val2_s[64];
  __shared__ float val3_s[64];
  int b = blockIdx.x, t = threadIdx.x;
  float s = part[(size_t)b * CTOT + t];
  if (t < CADV) adv_s[t] = fmaxf(s + advb[t], 0.f);
  else          v1_s[t - CADV] = fmaxf(s + v1b[t - CADV], 0.f);
  __syncthreads();
  if (t < 64) {
    float a = v2b[t];
#pragma unroll
    for (int i = 0; i < 64; ++i) a += v1_s[i] * v2w[i * 64 + t];
    val2_s[t] = fmaxf(a, 0.f);
  }
  __syncthreads();
  if (t < 64) {
    float a = v3b[t];
#pragma unroll
    for (int j = 0; j < 64; ++j) a += val2_s[j] * v3w[j * 64 + t];
    val3_s[t] = a;
  }
  __syncthreads();
  if (t < CADV) {
    int d = t / 3;
    float mean = (adv_s[d * 3] + adv_s[d * 3 + 1] + adv_s[d * 3 + 2]) * (1.f / 3.f);
    out[(size_t)b * CADV + t] = val3_s[d] + adv_s[t] - mean;
  }
}

extern "C" void kernel_launch(void* const* d_in, const int* in_sizes, int n_in,
                              void* d_out, int out_size, void* d_ws, size_t ws_size,
                              hipStream_t stream)
{
  (void)in_sizes; (void)n_in; (void)out_size; (void)ws_size;
  const float* x     = (const float*)d_in[0];
  const int*   ei    = (const int*)d_in[1];
  const float* w1    = (const float*)d_in[2];
  const float* b1    = (const float*)d_in[3];
  const float* w2    = (const float*)d_in[4];
  const float* b2    = (const float*)d_in[5];
  const float* rootw = (const float*)d_in[6];
  const float* convb = (const float*)d_in[7];
  const float* advw  = (const float*)d_in[8];
  const float* advb  = (const float*)d_in[9];
  const float* v1w   = (const float*)d_in[10];
  const float* v1b   = (const float*)d_in[11];
  const float* v2w   = (const float*)d_in[12];
  const float* v2b   = (const float*)d_in[13];
  const float* v3w   = (const float*)d_in[14];
  const float* v3b   = (const float*)d_in[15];
  float* out = (float*)d_out;

  const size_t wtB   = (size_t)Ktot * CTOT * 2;    // 16.8 MB
  const size_t featB = (size_t)Bsz * Ktot * 2;     // 67 MB
  const size_t partB = (size_t)Bsz * CTOT * 4;     // 1 MiB
  char* w = (char*)d_ws;
  unsigned short* wtp   = (unsigned short*)w;
  unsigned short* featp = (unsigned short*)(w + wtB);
  float* part = (float*)(w + wtB + featB);
  float* msg  = (float*)(w + wtB + featB + partB);     // 128 KB
  float* theta_ws = msg + Nn * OUTC;                   // fallback-only
  float* S_ws = theta_ws + 1024;

  int occ = 0;
  hipError_t oe = hipOccupancyMaxActiveBlocksPerMultiprocessor(&occ, mega, 256, 0);
  if (oe != hipSuccess || occ < 1) occ = 0;
  int gridsz = occ * 256;
  if (gridsz > 512) gridsz = 512;

  hipError_t le = hipErrorUnknown;
  if (gridsz >= 64) {
    void* args[] = {&x, &ei, &w1, &b1, &w2, &b2, &rootw, &convb, &advw, &advb,
                    &v1w, &v1b, &v2w, &v2b, &v3w, &v3b, &out,
                    &wtp, &featp, &part, &msg};
    le = hipLaunchCooperativeKernel((void*)mega, dim3(gridsz), dim3(256),
                                    args, 0, stream);
  }
  if (le != hipSuccess) {  // deterministic per-environment fallback (R6 path)
    prep_kernel<<<1033, 256, 0, stream>>>(advw, v1w, w1, b1, w2, b2, x, ei,
                                          wtp, theta_ws, S_ws);
    zero_kernel<<<Bsz * CTOT / 1024, 256, 0, stream>>>(part);
    feat_kernel<<<dim3(Nn / 4, 8), 256, 0, stream>>>(x, rootw, convb, theta_ws,
                                                     S_ws, featp);
    gemm_fb<<<dim3(16, 32), 256, 0, stream>>>(featp, wtp, part, 32);
    final_kernel<<<Bsz, 256, 0, stream>>>(part, advb, v1b, v2w, v2b, v3w, v3b, out);
  }
}

// Round 8
// 217.815 us; speedup vs baseline: 2.3344x; 2.3344x over previous
//
#include <hip/hip_runtime.h>

#define Bsz 1024
#define Nn 256
#define Fdim 8
#define Eedge 1024
#define OUTC 128
#define CADV 192
#define CTOT 256
#define Ktot 32768   // Nn * OUTC
#define ASTR 40      // LDS row stride in bf16 (32+8): 16B-aligned, 2-way banks (free)

typedef __attribute__((ext_vector_type(8))) short short8;
typedef __attribute__((ext_vector_type(4))) float float4v;

static __device__ inline unsigned short f2bf(float f) {
  union { float f; unsigned u; } v; v.f = f;
  unsigned r = v.u + 0x7FFFu + ((v.u >> 16) & 1u);  // round-nearest-even
  return (unsigned short)(r >> 16);
}
static __device__ inline uint4 pack8(const unsigned short* b) {
  uint4 v;
  v.x = (unsigned)b[0] | ((unsigned)b[1] << 16);
  v.y = (unsigned)b[2] | ((unsigned)b[3] << 16);
  v.z = (unsigned)b[4] | ((unsigned)b[5] << 16);
  v.w = (unsigned)b[6] | ((unsigned)b[7] << 16);
  return v;
}

// ---------------------------------------------------------------------------
// Prep (one dispatch, 1033 blocks):
//   bid <1024 : Wt[kt][c][32] bf16 transpose (LDS-staged, coalesced flush)
//   1024..1031: theta[1024] = edge-MLP output (identical for every edge)
//   1032      : S[n][f] = scatter-add of x[0,src,:] over edges targeting n
// ---------------------------------------------------------------------------
__global__ __launch_bounds__(256) void prep_kernel(
    const float* __restrict__ advw, const float* __restrict__ v1w,
    const float* __restrict__ w1, const float* __restrict__ b1,
    const float* __restrict__ w2, const float* __restrict__ b2,
    const float* __restrict__ x, const int* __restrict__ ei,
    unsigned short* __restrict__ wt, float* __restrict__ theta_ws,
    float* __restrict__ S_ws)
{
  int bid = blockIdx.x, t = threadIdx.x;
  if (bid < 1024) {
    __shared__ unsigned short st[CTOT * ASTR];  // 20 KB
    int kt = bid, c = t;
    const float* src; int stride, col;
    if (c < CADV) { src = advw; stride = CADV; col = c; }
    else          { src = v1w;  stride = 64;   col = c - CADV; }
    for (int p = 0; p < 4; ++p) {
      unsigned short buf[8];
#pragma unroll
      for (int i = 0; i < 8; ++i)
        buf[i] = f2bf(src[(size_t)(kt * 32 + p * 8 + i) * stride + col]);
      *(uint4*)(st + c * ASTR + p * 8) = pack8(buf);
    }
    __syncthreads();
    uint4* dst = (uint4*)(wt + (size_t)kt * (CTOT * 32));
    for (int r = 0; r < 4; ++r) {
      int s = r * 256 + c;        // lane-consecutive -> coalesced
      dst[s] = *(const uint4*)(st + (s >> 2) * ASTR + (s & 3) * 8);
    }
  } else if (bid < 1032) {
    __shared__ float h_s[64];
    if (t < 64) h_s[t] = fmaxf(w1[t] + b1[t], 0.f);
    __syncthreads();
    if (t < 128) {
      int c = (bid - 1024) * 128 + t;
      float acc = b2[c];
#pragma unroll
      for (int j = 0; j < 64; ++j) acc += h_s[j] * w2[j * 1024 + c];
      theta_ws[c] = acc;
    }
  } else {
    __shared__ float S_s[Nn * Fdim];
    __shared__ int is64_s;
    for (int i = t; i < Nn * Fdim; i += 256) S_s[i] = 0.f;
    if (t == 0) {
      int z = 0;
      for (int i = 1; i < 16; i += 2) z |= ei[i];
      is64_s = (z == 0);  // little-endian int64 detection
    }
    __syncthreads();
    int is64 = is64_s;
    for (int e = t; e < Eedge; e += 256) {
      int src, tgt;
      if (is64) { src = ei[2 * e]; tgt = ei[2 * (Eedge + e)]; }
      else      { src = ei[e];     tgt = ei[Eedge + e]; }
      src &= 255; tgt &= 255;
#pragma unroll
      for (int f = 0; f < Fdim; ++f)
        atomicAdd(&S_s[tgt * Fdim + f], x[src * Fdim + f]);
    }
    __syncthreads();
    for (int i = t; i < Nn * Fdim; i += 256) S_ws[i] = S_s[i];
  }
}

// ---------------------------------------------------------------------------
// feat bf16 -> feat[kt][b][32].  Block = 4 consecutive nodes x 128 batch rows
// (full 128-B x cachelines), msg computed inline for by==0, LDS-staged
// coalesced flush per node.
// ---------------------------------------------------------------------------
__global__ __launch_bounds__(256) void feat_kernel(
    const float* __restrict__ x, const float* __restrict__ rootw,
    const float* __restrict__ convb, const float* __restrict__ theta_ws,
    const float* __restrict__ S_ws, unsigned short* __restrict__ feat)
{
  __shared__ float rw_s[Fdim * OUTC];
  __shared__ float cb_s[OUTC];
  __shared__ float th_s[1024];
  __shared__ float Ssh[32];
  __shared__ float msg_s[4][OUTC];
  __shared__ unsigned short st[4 * 128 * ASTR];  // 40 KB
  int nb = blockIdx.x, by = blockIdx.y, t = threadIdx.x;
  for (int i = t; i < Fdim * OUTC; i += 256) rw_s[i] = rootw[i];
  if (t < OUTC) cb_s[t] = convb[t];
  if (by == 0) {
    for (int i = t; i < 1024; i += 256) th_s[i] = theta_ws[i];
    if (t < 32) Ssh[t] = S_ws[nb * 32 + t];
  }
  __syncthreads();
  if (by == 0) {
#pragma unroll
    for (int p = 0; p < 2; ++p) {
      int idx = p * 256 + t;
      int node = idx >> 7, o = idx & 127;
      float m = 0.f;
#pragma unroll
      for (int f = 0; f < Fdim; ++f) m += Ssh[node * 8 + f] * th_s[f * 128 + o];
      msg_s[node][o] = m;
    }
  }
  __syncthreads();
  int bl = t & 127, oh = t >> 7;
  int b = by * 128 + bl;
  bool isb0 = (b == 0);
  const float* xp = x + ((size_t)b * Nn + nb * 4) * Fdim;
  float xr[32];
#pragma unroll
  for (int p = 0; p < 8; ++p) *(float4*)(xr + 4 * p) = ((const float4*)xp)[p];
  for (int node = 0; node < 4; ++node) {
    for (int r = 0; r < 2; ++r) {
      int obase = oh * 64 + r * 32;
      int ktl = oh * 2 + r;
      for (int p = 0; p < 4; ++p) {
        unsigned short buf[8];
#pragma unroll
        for (int jj = 0; jj < 8; ++jj) {
          int o = obase + p * 8 + jj;
          float v = cb_s[o];
#pragma unroll
          for (int f = 0; f < Fdim; ++f) v += xr[node * 8 + f] * rw_s[f * OUTC + o];
          if (isb0) v += msg_s[node][o];
          buf[jj] = f2bf(fmaxf(v, 0.f));
        }
        *(uint4*)(st + (ktl * 128 + bl) * ASTR + p * 8) = pack8(buf);
      }
    }
    __syncthreads();
    int kt0 = (nb * 4 + node) * 4;
    for (int ktl = 0; ktl < 4; ++ktl) {
      uint4* dst = (uint4*)(feat + (((size_t)(kt0 + ktl)) * Bsz + by * 128) * 32);
      for (int p = 0; p < 2; ++p) {
        int s = p * 256 + t;   // lane-consecutive -> coalesced
        dst[s] = *(const uint4*)(st + (ktl * 128 + (s >> 2)) * ASTR + (s & 3) * 8);
      }
    }
    __syncthreads();
  }
}

// ---------------------------------------------------------------------------
// MFMA GEMM: part[ch][m][c] (fp32) = feat[m, kchunk] @ W[kchunk, c].
// Block: 512 thr = 8 waves (R4's proven-fast shape), tile 128m x 256c;
// wave grid 2x4, wave tile 64m x 64c = 4x4 MFMA tiles (16x16x32 bf16).
// KEY CHANGE vs R4/R6: mfma operands SWAPPED -> D[row=quad*4+reg]=c-dim,
// D[col=lane&15]=m-dim, so each lane's 4 acc regs are CONSECUTIVE c values
// => per-lane float4 epilogue (global_store_dwordx4). R2 measured this store
// class at WRITE_SIZE=ideal; R5/R6's scalar stores showed 3.6-5.8x HBM amp.
// Grid (8 mb, 64 ch) = 512 blocks = 2/CU; LDS 30 KB.
// ---------------------------------------------------------------------------
__global__ __launch_bounds__(512, 2) void gemm_mfma(
    const unsigned short* __restrict__ feat, const unsigned short* __restrict__ wt,
    float* __restrict__ part, int iters)
{
  __shared__ short a_s[128 * ASTR];   // 10 KB
  __shared__ short b_s[256 * ASTR];   // 20 KB
  int t = threadIdx.x;
  int mb = blockIdx.x;   // 0..7
  int ch = blockIdx.y;   // K chunk
  int wave = t >> 6, lane = t & 63;
  int wm = wave >> 2, wn = wave & 3;   // 2 x 4 wave grid
  int lm = lane & 15, lq = lane >> 4;

  float4v acc[4][4];   // [i: m-tile][j: c-tile]; reg r -> c = j*16 + lq*4 + r
#pragma unroll
  for (int i = 0; i < 4; ++i)
#pragma unroll
    for (int j = 0; j < 4; ++j) acc[i][j] = (float4v)0.f;

  for (int kk = 0; kk < iters; ++kk) {
    int kt = ch * iters + kk;
    const uint4* gB = (const uint4*)wt + (size_t)kt * 1024;              // 256c x 4
    const uint4* gA = (const uint4*)feat + (size_t)kt * 4096 + mb * 512; // 128m x 4
    uint4 vb0 = gB[t], vb1 = gB[t + 512];
    uint4 va  = gA[t];
    __syncthreads();  // previous tile fully consumed
    *(uint4*)(b_s + (t >> 2) * ASTR + (t & 3) * 8) = vb0;
    {
      int u = t + 512;
      *(uint4*)(b_s + (u >> 2) * ASTR + (u & 3) * 8) = vb1;
    }
    *(uint4*)(a_s + (t >> 2) * ASTR + (t & 3) * 8) = va;
    __syncthreads();
    short8 aF[4];
#pragma unroll
    for (int i = 0; i < 4; ++i)
      aF[i] = *(const short8*)(a_s + (wm * 64 + i * 16 + lm) * ASTR + lq * 8);
#pragma unroll
    for (int j = 0; j < 4; ++j) {
      short8 bF = *(const short8*)(b_s + (wn * 64 + j * 16 + lm) * ASTR + lq * 8);
#pragma unroll
      for (int i = 0; i < 4; ++i)
        acc[i][j] = __builtin_amdgcn_mfma_f32_16x16x32_bf16(bF, aF[i], acc[i][j], 0, 0, 0);
    }
  }

  // epilogue: per-lane dwordx4; lanes (lm fixed, lq 0..3) cover contiguous 64B
  float* pb = part + ((size_t)ch * Bsz + mb * 128) * CTOT;
#pragma unroll
  for (int i = 0; i < 4; ++i) {
    int m = wm * 64 + i * 16 + lm;
#pragma unroll
    for (int j = 0; j < 4; ++j) {
      int c = wn * 64 + j * 16 + lq * 4;
      *(float4v*)(pb + (size_t)m * CTOT + c) = acc[i][j];
    }
  }
}

// ---------------------------------------------------------------------------
// Final: reduce fp32 split-K partials, biases+relu, val MLP, dueling combine.
// ---------------------------------------------------------------------------
__global__ __launch_bounds__(256) void final_kernel(
    const float* __restrict__ part, int ns,
    const float* __restrict__ advb, const float* __restrict__ v1b,
    const float* __restrict__ v2w, const float* __restrict__ v2b,
    const float* __restrict__ v3w, const float* __restrict__ v3b,
    float* __restrict__ out)
{
  __shared__ float adv_s[CADV];
  __shared__ float v1_s[64];
  __shared__ float val2_s[64];
  __shared__ float val3_s[64];
  int b = blockIdx.x, t = threadIdx.x;
  float s = 0.f;
  const float* p = part + (size_t)b * CTOT + t;
  for (int i = 0; i < ns; ++i) s += p[(size_t)i * Bsz * CTOT];
  if (t < CADV) adv_s[t] = fmaxf(s + advb[t], 0.f);
  else          v1_s[t - CADV] = fmaxf(s + v1b[t - CADV], 0.f);
  __syncthreads();
  if (t < 64) {
    float a = v2b[t];
#pragma unroll
    for (int i = 0; i < 64; ++i) a += v1_s[i] * v2w[i * 64 + t];
    val2_s[t] = fmaxf(a, 0.f);
  }
  __syncthreads();
  if (t < 64) {
    float a = v3b[t];
#pragma unroll
    for (int j = 0; j < 64; ++j) a += val2_s[j] * v3w[j * 64 + t];
    val3_s[t] = a;
  }
  __syncthreads();
  if (t < CADV) {
    int d = t / 3;
    float mean = (adv_s[d * 3] + adv_s[d * 3 + 1] + adv_s[d * 3 + 2]) * (1.f / 3.f);
    out[(size_t)b * CADV + t] = val3_s[d] + adv_s[t] - mean;
  }
}

extern "C" void kernel_launch(void* const* d_in, const int* in_sizes, int n_in,
                              void* d_out, int out_size, void* d_ws, size_t ws_size,
                              hipStream_t stream)
{
  (void)in_sizes; (void)n_in; (void)out_size;
  const float* x     = (const float*)d_in[0];
  const int*   ei    = (const int*)d_in[1];
  const float* w1    = (const float*)d_in[2];
  const float* b1    = (const float*)d_in[3];
  const float* w2    = (const float*)d_in[4];
  const float* b2    = (const float*)d_in[5];
  const float* rootw = (const float*)d_in[6];
  const float* convb = (const float*)d_in[7];
  const float* advw  = (const float*)d_in[8];
  const float* advb  = (const float*)d_in[9];
  const float* v1w   = (const float*)d_in[10];
  const float* v1b   = (const float*)d_in[11];
  const float* v2w   = (const float*)d_in[12];
  const float* v2b   = (const float*)d_in[13];
  const float* v3w   = (const float*)d_in[14];
  const float* v3b   = (const float*)d_in[15];
  float* out = (float*)d_out;

  const size_t thB   = 16384;                          // theta 4K + S 8K + pad
  const size_t wtB   = (size_t)Ktot * CTOT * 2;        // 16.8 MB
  const size_t featB = (size_t)Bsz * Ktot * 2;         // 67 MB

  int NS = 64;   // proven: ws >= 151 MB (R3/R4 identical footprint ran)
  while (NS > 8 && thB + wtB + featB + (size_t)NS * Bsz * CTOT * 4 > ws_size)
    NS >>= 1;

  float* theta_ws = (float*)d_ws;
  float* S_ws     = (float*)((char*)d_ws + 4096);
  unsigned short* wtp   = (unsigned short*)((char*)d_ws + thB);
  unsigned short* featp = (unsigned short*)((char*)d_ws + thB + wtB);
  float* part = (float*)((char*)d_ws + thB + wtB + featB);

  prep_kernel<<<1033, 256, 0, stream>>>(advw, v1w, w1, b1, w2, b2, x, ei,
                                        wtp, theta_ws, S_ws);
  feat_kernel<<<dim3(Nn / 4, 8), 256, 0, stream>>>(x, rootw, convb, theta_ws,
                                                   S_ws, featp);
  gemm_mfma<<<dim3(8, NS), 512, 0, stream>>>(featp, wtp, part, 1024 / NS);
  final_kernel<<<Bsz, 256, 0, stream>>>(part, NS, advb, v1b, v2w, v2b, v3w, v3b, out);
}